// Round 1
// baseline (196.702 us; speedup 1.0000x reference)
//
#include <hip/hip_runtime.h>
#include <math.h>

// Problem constants (fixed by the reference): N=2097152, G=8192, T=1000.
#define GMAX 8192

// Device-global scratch (avoids any dependence on ws_size; fully rewritten
// every call, so no cross-call state).
__device__ float g_sched[4 * 1024];        // c0 | c1 | cs | isf, stride 1024
__device__ int   g_starts[GMAX + 1];       // segment boundaries of sorted batch
__device__ float g_gparams[GMAX * 16];     // per-graph: R[9], tvec[3], c0,c1,cs,isf

// ---------------------------------------------------------------------------
// K0: schedule buffers from beta. Single block, Hillis-Steele scan in LDS.
// fwd2[t] = cumsum(beta)[t]; bwd2[t] = total - fwd2[t] + beta[t]
// c0 = fwd2/denom, c1 = bwd2/denom, cs = sqrt(fwd2*bwd2/denom), isf = 1/sqrt(fwd2)
// ---------------------------------------------------------------------------
__global__ __launch_bounds__(1024) void k_sched(const float* __restrict__ beta, int T) {
    __shared__ double sbeta[1024];
    __shared__ double buf[2][1024];
    int t = threadIdx.x;
    double b = (t < T) ? (double)beta[t] : 0.0;
    sbeta[t] = b;
    buf[0][t] = b;
    __syncthreads();
    int src = 0;
    for (int off = 1; off < 1024; off <<= 1) {
        double v = buf[src][t];
        if (t >= off) v += buf[src][t - off];
        buf[src ^ 1][t] = v;
        src ^= 1;
        __syncthreads();
    }
    double total = buf[src][T - 1];
    if (t < T) {
        double fwd2 = buf[src][t];
        double bwd2 = total - fwd2 + sbeta[t];
        double denom = fwd2 + bwd2;
        g_sched[t]          = (float)(fwd2 / denom);
        g_sched[1024 + t]   = (float)(bwd2 / denom);
        g_sched[2048 + t]   = (float)sqrt(fwd2 * bwd2 / denom);
        g_sched[3072 + t]   = (float)(1.0 / sqrt(fwd2));
    }
}

// ---------------------------------------------------------------------------
// K1: start[g] = lower_bound(batch, g). batch is sorted, values in [0,G).
// ---------------------------------------------------------------------------
__global__ void k_starts(const int* __restrict__ batch, int N, int G) {
    int g = blockIdx.x * blockDim.x + threadIdx.x;
    if (g > G) return;
    int lo = 0, hi = N;
    while (lo < hi) {
        int mid = (lo + hi) >> 1;
        if (batch[mid] < g) lo = mid + 1; else hi = mid;
    }
    g_starts[g] = lo;
}

// ---------------------------------------------------------------------------
// Kabsch from raw sums (thread-0-only, double precision Jacobi on H^T H).
// sum = {Sx0[3], Sxt[3], M[9] = sum x0 xt^T (row-major)}
// H = M - Sx0 Sxt^T / n; A = H^T H = V diag(w) V^T; s = sqrt(w) desc;
// d = sign(det H); R = V diag(1/s1, 1/s2, d/s3) V^T H^T.
// ---------------------------------------------------------------------------
__device__ void kabsch_store(const float* sum, int n, float c0, float c1,
                             float cs, float isf, float* p) {
    double fn = (double)(n > 0 ? n : 1);
    double H[3][3];
    #pragma unroll
    for (int a = 0; a < 3; ++a)
        #pragma unroll
        for (int b = 0; b < 3; ++b)
            H[a][b] = (double)sum[6 + 3*a + b] - (double)sum[a] * (double)sum[3 + b] / fn;

    // A = H^T H (symmetric)
    double A[3][3];
    #pragma unroll
    for (int i = 0; i < 3; ++i)
        #pragma unroll
        for (int j = 0; j < 3; ++j) {
            double acc = 0.0;
            #pragma unroll
            for (int k = 0; k < 3; ++k) acc += H[k][i] * H[k][j];
            A[i][j] = acc;
        }

    double V[3][3] = {{1,0,0},{0,1,0},{0,0,1}};
    // Cyclic Jacobi
    for (int sweep = 0; sweep < 20; ++sweep) {
        double off = A[0][1]*A[0][1] + A[0][2]*A[0][2] + A[1][2]*A[1][2];
        double diag = A[0][0]*A[0][0] + A[1][1]*A[1][1] + A[2][2]*A[2][2];
        if (off <= 1e-28 * (diag + 1e-300)) break;
        for (int pi = 0; pi < 3; ++pi) {
            int P = (pi == 0) ? 0 : (pi == 1) ? 0 : 1;
            int Q = (pi == 0) ? 1 : (pi == 1) ? 2 : 2;
            double apq = A[P][Q];
            if (apq == 0.0) continue;
            double theta = (A[Q][Q] - A[P][P]) / (2.0 * apq);
            double tt = ((theta >= 0.0) ? 1.0 : -1.0) /
                        (fabs(theta) + sqrt(theta * theta + 1.0));
            double c = 1.0 / sqrt(tt * tt + 1.0);
            double s = tt * c;
            double app = A[P][P], aqq = A[Q][Q];
            A[P][P] = app - tt * apq;
            A[Q][Q] = aqq + tt * apq;
            A[P][Q] = A[Q][P] = 0.0;
            int Rr = 3 - P - Q;
            double arp = A[Rr][P], arq = A[Rr][Q];
            A[Rr][P] = A[P][Rr] = c * arp - s * arq;
            A[Rr][Q] = A[Q][Rr] = s * arp + c * arq;
            #pragma unroll
            for (int i = 0; i < 3; ++i) {
                double vip = V[i][P], viq = V[i][Q];
                V[i][P] = c * vip - s * viq;
                V[i][Q] = s * vip + c * viq;
            }
        }
    }
    double w[3] = {A[0][0], A[1][1], A[2][2]};
    int o0 = 0, o1 = 1, o2 = 2, tmp;
    if (w[o0] < w[o1]) { tmp = o0; o0 = o1; o1 = tmp; }
    if (w[o0] < w[o2]) { tmp = o0; o0 = o2; o2 = tmp; }
    if (w[o1] < w[o2]) { tmp = o1; o1 = o2; o2 = tmp; }

    double s0 = sqrt(fmax(w[o0], 0.0));
    double s1 = sqrt(fmax(w[o1], 0.0));
    double s2 = sqrt(fmax(w[o2], 0.0));
    double det = H[0][0]*(H[1][1]*H[2][2] - H[1][2]*H[2][1])
               - H[0][1]*(H[1][0]*H[2][2] - H[1][2]*H[2][0])
               + H[0][2]*(H[1][0]*H[2][1] - H[1][1]*H[2][0]);
    double d = (det >= 0.0) ? 1.0 : -1.0;
    double thr = 1e-9 * s0;
    double i0 = (s0 > 1e-300) ? 1.0 / s0 : 0.0;
    double i1 = (s1 > thr) ? 1.0 / s1 : 0.0;
    double i2 = (s2 > thr) ? d / s2 : 0.0;

    // B = V diag(i0,i1,i2-ordered) V^T
    double B[3][3];
    #pragma unroll
    for (int i = 0; i < 3; ++i)
        #pragma unroll
        for (int j = 0; j < 3; ++j)
            B[i][j] = V[i][o0] * i0 * V[j][o0]
                    + V[i][o1] * i1 * V[j][o1]
                    + V[i][o2] * i2 * V[j][o2];

    // R = B H^T ; tvec = comt - R com0
    double Rm[3][3];
    #pragma unroll
    for (int i = 0; i < 3; ++i)
        #pragma unroll
        for (int j = 0; j < 3; ++j)
            Rm[i][j] = B[i][0]*H[j][0] + B[i][1]*H[j][1] + B[i][2]*H[j][2];

    double com0[3], comt[3];
    #pragma unroll
    for (int a = 0; a < 3; ++a) { com0[a] = sum[a] / fn; comt[a] = sum[3+a] / fn; }

    #pragma unroll
    for (int i = 0; i < 3; ++i)
        #pragma unroll
        for (int j = 0; j < 3; ++j)
            p[3*i + j] = (float)Rm[i][j];
    #pragma unroll
    for (int i = 0; i < 3; ++i)
        p[9 + i] = (float)(comt[i] - (Rm[i][0]*com0[0] + Rm[i][1]*com0[1] + Rm[i][2]*com0[2]));
    p[12] = c0; p[13] = c1; p[14] = cs; p[15] = isf;
}

// ---------------------------------------------------------------------------
// K2: one block per graph. Single pass: compute x_t (write to out), accumulate
// {Sx0, Sxt, M=sum x0 xt^T}; block-reduce 15 floats; thread 0 does Kabsch.
// ---------------------------------------------------------------------------
__global__ __launch_bounds__(256) void k_reduce(const float* __restrict__ x0,
                                               const float* __restrict__ x1,
                                               const float* __restrict__ noise,
                                               const int* __restrict__ tarr,
                                               float* __restrict__ out_xt) {
    int g = blockIdx.x;
    int s = g_starts[g], e = g_starts[g + 1];
    int tg = tarr[g];
    float c0 = g_sched[tg];
    float c1 = g_sched[1024 + tg];
    float cs = g_sched[2048 + tg];
    float isf = g_sched[3072 + tg];

    float acc[15];
    #pragma unroll
    for (int k = 0; k < 15; ++k) acc[k] = 0.0f;

    for (int i = s + (int)threadIdx.x; i < e; i += 256) {
        float a0 = x0[3*i], a1 = x0[3*i+1], a2 = x0[3*i+2];
        float b0 = x1[3*i], b1 = x1[3*i+1], b2 = x1[3*i+2];
        float n0 = noise[3*i], n1 = noise[3*i+1], n2 = noise[3*i+2];
        float t0 = c0*a0 + c1*b0 + cs*n0;
        float t1 = c0*a1 + c1*b1 + cs*n1;
        float t2 = c0*a2 + c1*b2 + cs*n2;
        out_xt[3*i] = t0; out_xt[3*i+1] = t1; out_xt[3*i+2] = t2;
        acc[0] += a0; acc[1] += a1; acc[2] += a2;
        acc[3] += t0; acc[4] += t1; acc[5] += t2;
        acc[6]  += a0*t0; acc[7]  += a0*t1; acc[8]  += a0*t2;
        acc[9]  += a1*t0; acc[10] += a1*t1; acc[11] += a1*t2;
        acc[12] += a2*t0; acc[13] += a2*t1; acc[14] += a2*t2;
    }

    // wave (64-lane) shuffle reduce, then cross-wave via LDS
    #pragma unroll
    for (int k = 0; k < 15; ++k) {
        #pragma unroll
        for (int off = 32; off > 0; off >>= 1)
            acc[k] += __shfl_down(acc[k], off, 64);
    }
    __shared__ float red[4][15];
    int wid = threadIdx.x >> 6, lane = threadIdx.x & 63;
    if (lane == 0) {
        #pragma unroll
        for (int k = 0; k < 15; ++k) red[wid][k] = acc[k];
    }
    __syncthreads();
    if (threadIdx.x == 0) {
        float sum[15];
        #pragma unroll
        for (int k = 0; k < 15; ++k)
            sum[k] = red[0][k] + red[1][k] + red[2][k] + red[3][k];
        kabsch_store(sum, e - s, c0, c1, cs, isf, &g_gparams[g * 16]);
    }
}

// ---------------------------------------------------------------------------
// K3: per node: target = (x_t - (R x0 + tvec)) * isf
// ---------------------------------------------------------------------------
__global__ __launch_bounds__(256) void k_final(const float* __restrict__ x0,
                                              const int* __restrict__ batch,
                                              const float* __restrict__ xt,
                                              float* __restrict__ out_tg,
                                              int N) {
    int i = blockIdx.x * 256 + (int)threadIdx.x;
    if (i >= N) return;
    int g = batch[i];
    const float* p = &g_gparams[g * 16];
    float a0 = x0[3*i], a1 = x0[3*i+1], a2 = x0[3*i+2];
    float t0 = xt[3*i], t1 = xt[3*i+1], t2 = xt[3*i+2];
    float al0 = p[0]*a0 + p[1]*a1 + p[2]*a2 + p[9];
    float al1 = p[3]*a0 + p[4]*a1 + p[5]*a2 + p[10];
    float al2 = p[6]*a0 + p[7]*a1 + p[8]*a2 + p[11];
    float isf = p[15];
    out_tg[3*i]   = (t0 - al0) * isf;
    out_tg[3*i+1] = (t1 - al1) * isf;
    out_tg[3*i+2] = (t2 - al2) * isf;
}

extern "C" void kernel_launch(void* const* d_in, const int* in_sizes, int n_in,
                              void* d_out, int out_size, void* d_ws, size_t ws_size,
                              hipStream_t stream) {
    const float* x0    = (const float*)d_in[0];
    const float* x1    = (const float*)d_in[1];
    const float* noise = (const float*)d_in[2];
    const float* beta  = (const float*)d_in[3];
    const int*   batch = (const int*)d_in[4];
    const int*   tarr  = (const int*)d_in[5];

    int N = in_sizes[4];      // 2097152
    int T = in_sizes[3];      // 1000
    int G = GMAX;             // 8192 (fixed by problem)

    float* out_xt = (float*)d_out;
    float* out_tg = out_xt + (size_t)3 * N;

    k_sched<<<1, 1024, 0, stream>>>(beta, T);
    k_starts<<<(G + 1 + 255) / 256, 256, 0, stream>>>(batch, N, G);
    k_reduce<<<G, 256, 0, stream>>>(x0, x1, noise, tarr, out_xt);
    k_final<<<(N + 255) / 256, 256, 0, stream>>>(x0, batch, out_xt, out_tg, N);
}

// Round 2
// 175.030 us; speedup vs baseline: 1.1238x; 1.1238x over previous
//
#include <hip/hip_runtime.h>
#include <math.h>

// Problem constants (fixed by the reference): N=2097152, G=8192, T=1000.
#define GMAX 8192

// Device-global scratch, fully rewritten every call (no cross-call state).
__device__ float g_sched[4 * 1024];        // c0 | c1 | cs | isf, stride 1024
__device__ int   g_starts[GMAX + 1];       // segment boundaries of sorted batch
__device__ float g_sums[GMAX * 16];        // per-graph raw sums (15 used)
__device__ float g_gparams[GMAX * 16];     // per-graph: R[9], tvec[3], c0,c1,cs,isf

// ---------------------------------------------------------------------------
// K0 (fused): block 0 = schedule scan; blocks 1.. = segment starts.
// ---------------------------------------------------------------------------
__global__ __launch_bounds__(1024) void k_prep(const float* __restrict__ beta,
                                               const int* __restrict__ batch,
                                               int T, int N, int G) {
    if (blockIdx.x == 0) {
        __shared__ double sbeta[1024];
        __shared__ double buf[2][1024];
        int t = threadIdx.x;
        double b = (t < T) ? (double)beta[t] : 0.0;
        sbeta[t] = b;
        buf[0][t] = b;
        __syncthreads();
        int src = 0;
        for (int off = 1; off < 1024; off <<= 1) {
            double v = buf[src][t];
            if (t >= off) v += buf[src][t - off];
            buf[src ^ 1][t] = v;
            src ^= 1;
            __syncthreads();
        }
        double total = buf[src][T - 1];
        if (t < T) {
            double fwd2 = buf[src][t];
            double bwd2 = total - fwd2 + sbeta[t];
            double denom = fwd2 + bwd2;
            g_sched[t]        = (float)(fwd2 / denom);
            g_sched[1024 + t] = (float)(bwd2 / denom);
            g_sched[2048 + t] = (float)sqrt(fwd2 * bwd2 / denom);
            g_sched[3072 + t] = (float)(1.0 / sqrt(fwd2));
        }
    } else {
        int g = (int)(blockIdx.x - 1) * 1024 + (int)threadIdx.x;
        if (g <= G) {
            int lo = 0, hi = N;
            while (lo < hi) {
                int mid = (lo + hi) >> 1;
                if (batch[mid] < g) lo = mid + 1; else hi = mid;
            }
            g_starts[g] = lo;
        }
    }
}

// ---------------------------------------------------------------------------
// Kabsch from raw sums (double precision Jacobi on H^T H). Per-thread.
// sum = {Sx0[3], Sxt[3], M[9] = sum x0 xt^T (row-major)}
// H = M - Sx0 Sxt^T / n; A = H^T H = V diag(w) V^T; s = sqrt(w) desc;
// d = sign(det H); R = V diag(1/s1, 1/s2, d/s3) V^T H^T.
// ---------------------------------------------------------------------------
__device__ void kabsch_store(const float* sum, int n, float c0, float c1,
                             float cs, float isf, float* p) {
    double fn = (double)(n > 0 ? n : 1);
    double H[3][3];
    #pragma unroll
    for (int a = 0; a < 3; ++a)
        #pragma unroll
        for (int b = 0; b < 3; ++b)
            H[a][b] = (double)sum[6 + 3*a + b] - (double)sum[a] * (double)sum[3 + b] / fn;

    double A[3][3];
    #pragma unroll
    for (int i = 0; i < 3; ++i)
        #pragma unroll
        for (int j = 0; j < 3; ++j) {
            double acc = 0.0;
            #pragma unroll
            for (int k = 0; k < 3; ++k) acc += H[k][i] * H[k][j];
            A[i][j] = acc;
        }

    double V[3][3] = {{1,0,0},{0,1,0},{0,0,1}};
    for (int sweep = 0; sweep < 20; ++sweep) {
        double off = A[0][1]*A[0][1] + A[0][2]*A[0][2] + A[1][2]*A[1][2];
        double diag = A[0][0]*A[0][0] + A[1][1]*A[1][1] + A[2][2]*A[2][2];
        if (off <= 1e-28 * (diag + 1e-300)) break;
        for (int pi = 0; pi < 3; ++pi) {
            int P = (pi == 0) ? 0 : (pi == 1) ? 0 : 1;
            int Q = (pi == 0) ? 1 : (pi == 1) ? 2 : 2;
            double apq = A[P][Q];
            if (apq == 0.0) continue;
            double theta = (A[Q][Q] - A[P][P]) / (2.0 * apq);
            double tt = ((theta >= 0.0) ? 1.0 : -1.0) /
                        (fabs(theta) + sqrt(theta * theta + 1.0));
            double c = 1.0 / sqrt(tt * tt + 1.0);
            double s = tt * c;
            double apq2 = A[P][Q];
            A[P][P] -= tt * apq2;
            A[Q][Q] += tt * apq2;
            A[P][Q] = A[Q][P] = 0.0;
            int Rr = 3 - P - Q;
            double arp = A[Rr][P], arq = A[Rr][Q];
            A[Rr][P] = A[P][Rr] = c * arp - s * arq;
            A[Rr][Q] = A[Q][Rr] = s * arp + c * arq;
            #pragma unroll
            for (int i = 0; i < 3; ++i) {
                double vip = V[i][P], viq = V[i][Q];
                V[i][P] = c * vip - s * viq;
                V[i][Q] = s * vip + c * viq;
            }
        }
    }
    double w[3] = {A[0][0], A[1][1], A[2][2]};
    int o0 = 0, o1 = 1, o2 = 2, tmp;
    if (w[o0] < w[o1]) { tmp = o0; o0 = o1; o1 = tmp; }
    if (w[o0] < w[o2]) { tmp = o0; o0 = o2; o2 = tmp; }
    if (w[o1] < w[o2]) { tmp = o1; o1 = o2; o2 = tmp; }

    double s0 = sqrt(fmax(w[o0], 0.0));
    double s1 = sqrt(fmax(w[o1], 0.0));
    double s2 = sqrt(fmax(w[o2], 0.0));
    double det = H[0][0]*(H[1][1]*H[2][2] - H[1][2]*H[2][1])
               - H[0][1]*(H[1][0]*H[2][2] - H[1][2]*H[2][0])
               + H[0][2]*(H[1][0]*H[2][1] - H[1][1]*H[2][0]);
    double d = (det >= 0.0) ? 1.0 : -1.0;
    double thr = 1e-9 * s0;
    double i0 = (s0 > 1e-300) ? 1.0 / s0 : 0.0;
    double i1 = (s1 > thr) ? 1.0 / s1 : 0.0;
    double i2 = (s2 > thr) ? d / s2 : 0.0;

    double B[3][3];
    #pragma unroll
    for (int i = 0; i < 3; ++i)
        #pragma unroll
        for (int j = 0; j < 3; ++j)
            B[i][j] = V[i][o0] * i0 * V[j][o0]
                    + V[i][o1] * i1 * V[j][o1]
                    + V[i][o2] * i2 * V[j][o2];

    double Rm[3][3];
    #pragma unroll
    for (int i = 0; i < 3; ++i)
        #pragma unroll
        for (int j = 0; j < 3; ++j)
            Rm[i][j] = B[i][0]*H[j][0] + B[i][1]*H[j][1] + B[i][2]*H[j][2];

    double com0[3], comt[3];
    #pragma unroll
    for (int a = 0; a < 3; ++a) { com0[a] = sum[a] / fn; comt[a] = sum[3+a] / fn; }

    #pragma unroll
    for (int i = 0; i < 3; ++i)
        #pragma unroll
        for (int j = 0; j < 3; ++j)
            p[3*i + j] = (float)Rm[i][j];
    #pragma unroll
    for (int i = 0; i < 3; ++i)
        p[9 + i] = (float)(comt[i] - (Rm[i][0]*com0[0] + Rm[i][1]*com0[1] + Rm[i][2]*com0[2]));
    p[12] = c0; p[13] = c1; p[14] = cs; p[15] = isf;
}

// ---------------------------------------------------------------------------
// K2: one block per graph. LDS-staged float4 loads; compute x_t (scalar store,
// inside segment only); accumulate {Sx0, Sxt, M}; LDS transpose reduce;
// store 15 raw sums. No Kabsch here.
// ---------------------------------------------------------------------------
__global__ __launch_bounds__(256) void k_reduce(const float* __restrict__ x0,
                                                const float* __restrict__ x1,
                                                const float* __restrict__ noise,
                                                const int* __restrict__ tarr,
                                                float* __restrict__ out_xt,
                                                int total4) {
    __shared__ __align__(16) float sA[776];
    __shared__ __align__(16) float sB[776];
    __shared__ __align__(16) float sN[776];
    __shared__ float red[15][257];

    int g = blockIdx.x;
    int s = g_starts[g], e = g_starts[g + 1];
    int tg = tarr[g];
    float c0 = g_sched[tg];
    float c1 = g_sched[1024 + tg];
    float cs = g_sched[2048 + tg];

    float acc[15];
    #pragma unroll
    for (int k = 0; k < 15; ++k) acc[k] = 0.0f;

    const int tid = (int)threadIdx.x;

    for (int cb = s; cb < e; cb += 256) {
        int m = e - cb; if (m > 256) m = 256;
        int fb = (3 * cb) & ~3;
        int nf4 = ((3 * (cb + m)) - fb + 3) >> 2;
        if (tid < nf4) {
            int i4 = (fb >> 2) + tid;
            if (i4 < total4) {
                ((float4*)sA)[tid] = ((const float4*)x0)[i4];
                ((float4*)sB)[tid] = ((const float4*)x1)[i4];
                ((float4*)sN)[tid] = ((const float4*)noise)[i4];
            }
        }
        __syncthreads();
        if (tid < m) {
            int off = 3 * (cb + tid) - fb;
            float a0 = sA[off], a1 = sA[off+1], a2 = sA[off+2];
            float b0 = sB[off], b1 = sB[off+1], b2 = sB[off+2];
            float n0 = sN[off], n1 = sN[off+1], n2 = sN[off+2];
            float t0 = c0*a0 + c1*b0 + cs*n0;
            float t1 = c0*a1 + c1*b1 + cs*n1;
            float t2 = c0*a2 + c1*b2 + cs*n2;
            int oi = 3 * (cb + tid);
            out_xt[oi] = t0; out_xt[oi+1] = t1; out_xt[oi+2] = t2;
            acc[0] += a0; acc[1] += a1; acc[2] += a2;
            acc[3] += t0; acc[4] += t1; acc[5] += t2;
            acc[6]  += a0*t0; acc[7]  += a0*t1; acc[8]  += a0*t2;
            acc[9]  += a1*t0; acc[10] += a1*t1; acc[11] += a1*t2;
            acc[12] += a2*t0; acc[13] += a2*t1; acc[14] += a2*t2;
        }
        __syncthreads();
    }

    // Block-level transpose reduce: 15 LDS writes + 16 strided reads + 4 shfl.
    #pragma unroll
    for (int v = 0; v < 15; ++v) red[v][tid] = acc[v];
    __syncthreads();
    int wv = tid >> 6;
    int lane = tid & 63;
    int v = wv * 4 + (lane >> 4);   // 0..15 (15 unused)
    int sub = lane & 15;
    float x = 0.0f;
    if (v < 15) {
        #pragma unroll
        for (int k = 0; k < 16; ++k) x += red[v][sub + (k << 4)];
    }
    x += __shfl_down(x, 8, 64);
    x += __shfl_down(x, 4, 64);
    x += __shfl_down(x, 2, 64);
    x += __shfl_down(x, 1, 64);
    if (v < 15 && sub == 0) g_sums[g * 16 + v] = x;
}

// ---------------------------------------------------------------------------
// K2b: one thread per graph — Kabsch (double Jacobi), fully parallel.
// ---------------------------------------------------------------------------
__global__ __launch_bounds__(256) void k_kabsch(const int* __restrict__ tarr) {
    int g = blockIdx.x * 256 + (int)threadIdx.x;
    if (g >= GMAX) return;
    float sum[15];
    #pragma unroll
    for (int k = 0; k < 15; ++k) sum[k] = g_sums[g * 16 + k];
    int n = g_starts[g + 1] - g_starts[g];
    int tg = tarr[g];
    float c0 = g_sched[tg];
    float c1 = g_sched[1024 + tg];
    float cs = g_sched[2048 + tg];
    float isf = g_sched[3072 + tg];
    kabsch_store(sum, n, c0, c1, cs, isf, &g_gparams[g * 16]);
}

// ---------------------------------------------------------------------------
// K3: one block per graph. Params loaded once (uniform); LDS-staged float4
// loads of x0 and x_t; target = (x_t - (R x0 + tvec)) * isf.
// ---------------------------------------------------------------------------
__global__ __launch_bounds__(256) void k_final(const float* __restrict__ x0,
                                               const float* __restrict__ xt,
                                               float* __restrict__ out_tg,
                                               int total4) {
    __shared__ __align__(16) float sA[776];
    __shared__ __align__(16) float sT[776];
    int g = blockIdx.x;
    int s = g_starts[g], e = g_starts[g + 1];
    if (s >= e) return;   // uniform across block; no barrier reached

    const float* p = &g_gparams[g * 16];
    float r00 = p[0], r01 = p[1], r02 = p[2];
    float r10 = p[3], r11 = p[4], r12 = p[5];
    float r20 = p[6], r21 = p[7], r22 = p[8];
    float tv0 = p[9], tv1 = p[10], tv2 = p[11];
    float isf = p[15];

    const int tid = (int)threadIdx.x;
    for (int cb = s; cb < e; cb += 256) {
        int m = e - cb; if (m > 256) m = 256;
        int fb = (3 * cb) & ~3;
        int nf4 = ((3 * (cb + m)) - fb + 3) >> 2;
        if (tid < nf4) {
            int i4 = (fb >> 2) + tid;
            if (i4 < total4) {
                ((float4*)sA)[tid] = ((const float4*)x0)[i4];
                ((float4*)sT)[tid] = ((const float4*)xt)[i4];
            }
        }
        __syncthreads();
        if (tid < m) {
            int off = 3 * (cb + tid) - fb;
            float a0 = sA[off], a1 = sA[off+1], a2 = sA[off+2];
            float w0 = sT[off], w1 = sT[off+1], w2 = sT[off+2];
            float al0 = r00*a0 + r01*a1 + r02*a2 + tv0;
            float al1 = r10*a0 + r11*a1 + r12*a2 + tv1;
            float al2 = r20*a0 + r21*a1 + r22*a2 + tv2;
            int oi = 3 * (cb + tid);
            out_tg[oi]   = (w0 - al0) * isf;
            out_tg[oi+1] = (w1 - al1) * isf;
            out_tg[oi+2] = (w2 - al2) * isf;
        }
        __syncthreads();
    }
}

extern "C" void kernel_launch(void* const* d_in, const int* in_sizes, int n_in,
                              void* d_out, int out_size, void* d_ws, size_t ws_size,
                              hipStream_t stream) {
    const float* x0    = (const float*)d_in[0];
    const float* x1    = (const float*)d_in[1];
    const float* noise = (const float*)d_in[2];
    const float* beta  = (const float*)d_in[3];
    const int*   batch = (const int*)d_in[4];
    const int*   tarr  = (const int*)d_in[5];

    int N = in_sizes[4];      // 2097152
    int T = in_sizes[3];      // 1000
    int G = GMAX;             // 8192 (fixed by problem)
    int total4 = (3 * N) >> 2;

    float* out_xt = (float*)d_out;
    float* out_tg = out_xt + (size_t)3 * N;

    k_prep<<<1 + (G + 1 + 1023) / 1024, 1024, 0, stream>>>(beta, batch, T, N, G);
    k_reduce<<<G, 256, 0, stream>>>(x0, x1, noise, tarr, out_xt, total4);
    k_kabsch<<<(G + 255) / 256, 256, 0, stream>>>(tarr);
    k_final<<<G, 256, 0, stream>>>(x0, out_xt, out_tg, total4);
}

// Round 3
// 168.347 us; speedup vs baseline: 1.1684x; 1.0397x over previous
//
#include <hip/hip_runtime.h>
#include <math.h>

// Problem constants (fixed by the reference): N=2097152, G=8192, T=1000.
// N = 4 nodes/thread * 256 threads * 2048 blocks exactly.
#define GMAX 8192

// Device-global scratch, fully rewritten every call (no cross-call state).
__device__ float g_sched[4 * 1024];     // c0 | c1 | cs | isf, stride 1024
__device__ float g_sums[GMAX * 16];     // per-graph {Sx0[3],Sxt[3],M[9],count}
__device__ float g_gparams[GMAX * 16];  // per-graph: R[9], tvec[3], c0,c1,cs,isf

// ---------------------------------------------------------------------------
// K0: block 0 = schedule scan (validated in R1/R2); blocks 1..32 zero g_sums.
// ---------------------------------------------------------------------------
__global__ __launch_bounds__(1024) void k_prep(const float* __restrict__ beta, int T) {
    if (blockIdx.x == 0) {
        __shared__ double sbeta[1024];
        __shared__ double buf[2][1024];
        int t = threadIdx.x;
        double b = (t < T) ? (double)beta[t] : 0.0;
        sbeta[t] = b;
        buf[0][t] = b;
        __syncthreads();
        int src = 0;
        for (int off = 1; off < 1024; off <<= 1) {
            double v = buf[src][t];
            if (t >= off) v += buf[src][t - off];
            buf[src ^ 1][t] = v;
            src ^= 1;
            __syncthreads();
        }
        double total = buf[src][T - 1];
        if (t < T) {
            double fwd2 = buf[src][t];
            double bwd2 = total - fwd2 + sbeta[t];
            double denom = fwd2 + bwd2;
            g_sched[t]        = (float)(fwd2 / denom);
            g_sched[1024 + t] = (float)(bwd2 / denom);
            g_sched[2048 + t] = (float)sqrt(fwd2 * bwd2 / denom);
            g_sched[3072 + t] = (float)(1.0 / sqrt(fwd2));
        }
    } else {
        // 32 blocks * 1024 threads * 1 float4 = 131072 floats = GMAX*16
        int i = (int)(blockIdx.x - 1) * 1024 + (int)threadIdx.x;
        ((float4*)g_sums)[i] = make_float4(0.f, 0.f, 0.f, 0.f);
    }
}

__device__ inline void flush16(int g, const float* acc) {
    float* dst = &g_sums[g * 16];
    #pragma unroll
    for (int k = 0; k < 16; ++k) atomicAdd(dst + k, acc[k]);
}

// ---------------------------------------------------------------------------
// K1: 4 nodes/thread, fully coalesced float4 loads (no LDS, no barriers).
// Compute x_t -> out; accumulate {Sx0,Sxt,M,count} per graph-run; wave-level
// segmented suffix reduce (batch sorted => runs contiguous); run-head lanes
// atomicAdd 16 values.
// ---------------------------------------------------------------------------
__global__ __launch_bounds__(256) void k_accum(const float* __restrict__ x0,
                                               const float* __restrict__ x1,
                                               const float* __restrict__ noise,
                                               const int* __restrict__ batch,
                                               const int* __restrict__ tarr,
                                               float* __restrict__ out_xt) {
    const int t = (int)blockIdx.x * 256 + (int)threadIdx.x;   // 0..524287
    const int4 gb = ((const int4*)batch)[t];
    const int gs[4] = {gb.x, gb.y, gb.z, gb.w};

    const float4* X0 = (const float4*)x0;
    const float4* X1 = (const float4*)x1;
    const float4* XN = (const float4*)noise;
    float ax[12], bx[12], nx[12], tx[12];
    #pragma unroll
    for (int q = 0; q < 3; ++q) {
        *(float4*)&ax[4*q] = X0[3*t + q];
        *(float4*)&bx[4*q] = X1[3*t + q];
        *(float4*)&nx[4*q] = XN[3*t + q];
    }

    float acc[16];
    #pragma unroll
    for (int k = 0; k < 16; ++k) acc[k] = 0.0f;

    int gcur = gs[0];
    int tg = tarr[gcur];
    float c0 = g_sched[tg], c1 = g_sched[1024 + tg], cs = g_sched[2048 + tg];

    #pragma unroll
    for (int j = 0; j < 4; ++j) {
        if (gs[j] != gcur) {            // rare (~1.2% of threads)
            flush16(gcur, acc);
            #pragma unroll
            for (int k = 0; k < 16; ++k) acc[k] = 0.0f;
            gcur = gs[j];
            tg = tarr[gcur];
            c0 = g_sched[tg]; c1 = g_sched[1024 + tg]; cs = g_sched[2048 + tg];
        }
        float a0 = ax[3*j], a1 = ax[3*j+1], a2 = ax[3*j+2];
        float t0 = c0*a0 + c1*bx[3*j]   + cs*nx[3*j];
        float t1 = c0*a1 + c1*bx[3*j+1] + cs*nx[3*j+1];
        float t2 = c0*a2 + c1*bx[3*j+2] + cs*nx[3*j+2];
        tx[3*j] = t0; tx[3*j+1] = t1; tx[3*j+2] = t2;
        acc[0] += a0; acc[1] += a1; acc[2] += a2;
        acc[3] += t0; acc[4] += t1; acc[5] += t2;
        acc[6]  += a0*t0; acc[7]  += a0*t1; acc[8]  += a0*t2;
        acc[9]  += a1*t0; acc[10] += a1*t1; acc[11] += a1*t2;
        acc[12] += a2*t0; acc[13] += a2*t1; acc[14] += a2*t2;
        acc[15] += 1.0f;
    }

    float4* OUT = (float4*)out_xt;
    #pragma unroll
    for (int q = 0; q < 3; ++q) OUT[3*t + q] = *(const float4*)&tx[4*q];

    // Wave segmented suffix reduce over (gcur, acc). g non-decreasing by lane.
    const int lane = (int)threadIdx.x & 63;
    #pragma unroll
    for (int off = 1; off < 64; off <<= 1) {
        int gq = __shfl_down(gcur, off, 64);
        bool valid = (lane + off < 64) && (gq == gcur);
        #pragma unroll
        for (int k = 0; k < 16; ++k) {
            float xq = __shfl_down(acc[k], off, 64);
            if (valid) acc[k] += xq;
        }
    }
    int gprev = __shfl_up(gcur, 1, 64);
    if (lane == 0 || gprev != gcur) flush16(gcur, acc);
}

// ---------------------------------------------------------------------------
// Kabsch from raw sums (double Jacobi on H^T H) — math validated in R1/R2.
// ---------------------------------------------------------------------------
__device__ void kabsch_store(const float* sum, int n, float c0, float c1,
                             float cs, float isf, float* p) {
    double fn = (double)(n > 0 ? n : 1);
    double H[3][3];
    #pragma unroll
    for (int a = 0; a < 3; ++a)
        #pragma unroll
        for (int b = 0; b < 3; ++b)
            H[a][b] = (double)sum[6 + 3*a + b] - (double)sum[a] * (double)sum[3 + b] / fn;

    double A[3][3];
    #pragma unroll
    for (int i = 0; i < 3; ++i)
        #pragma unroll
        for (int j = 0; j < 3; ++j) {
            double acc = 0.0;
            #pragma unroll
            for (int k = 0; k < 3; ++k) acc += H[k][i] * H[k][j];
            A[i][j] = acc;
        }

    double V[3][3] = {{1,0,0},{0,1,0},{0,0,1}};
    for (int sweep = 0; sweep < 20; ++sweep) {
        double off = A[0][1]*A[0][1] + A[0][2]*A[0][2] + A[1][2]*A[1][2];
        double diag = A[0][0]*A[0][0] + A[1][1]*A[1][1] + A[2][2]*A[2][2];
        if (off <= 1e-28 * (diag + 1e-300)) break;
        for (int pi = 0; pi < 3; ++pi) {
            int P = (pi == 0) ? 0 : (pi == 1) ? 0 : 1;
            int Q = (pi == 0) ? 1 : (pi == 1) ? 2 : 2;
            double apq = A[P][Q];
            if (apq == 0.0) continue;
            double theta = (A[Q][Q] - A[P][P]) / (2.0 * apq);
            double tt = ((theta >= 0.0) ? 1.0 : -1.0) /
                        (fabs(theta) + sqrt(theta * theta + 1.0));
            double c = 1.0 / sqrt(tt * tt + 1.0);
            double s = tt * c;
            A[P][P] -= tt * apq;
            A[Q][Q] += tt * apq;
            A[P][Q] = A[Q][P] = 0.0;
            int Rr = 3 - P - Q;
            double arp = A[Rr][P], arq = A[Rr][Q];
            A[Rr][P] = A[P][Rr] = c * arp - s * arq;
            A[Rr][Q] = A[Q][Rr] = s * arp + c * arq;
            #pragma unroll
            for (int i = 0; i < 3; ++i) {
                double vip = V[i][P], viq = V[i][Q];
                V[i][P] = c * vip - s * viq;
                V[i][Q] = s * vip + c * viq;
            }
        }
    }
    double w[3] = {A[0][0], A[1][1], A[2][2]};
    int o0 = 0, o1 = 1, o2 = 2, tmp;
    if (w[o0] < w[o1]) { tmp = o0; o0 = o1; o1 = tmp; }
    if (w[o0] < w[o2]) { tmp = o0; o0 = o2; o2 = tmp; }
    if (w[o1] < w[o2]) { tmp = o1; o1 = o2; o2 = tmp; }

    double s0 = sqrt(fmax(w[o0], 0.0));
    double s1 = sqrt(fmax(w[o1], 0.0));
    double s2 = sqrt(fmax(w[o2], 0.0));
    double det = H[0][0]*(H[1][1]*H[2][2] - H[1][2]*H[2][1])
               - H[0][1]*(H[1][0]*H[2][2] - H[1][2]*H[2][0])
               + H[0][2]*(H[1][0]*H[2][1] - H[1][1]*H[2][0]);
    double d = (det >= 0.0) ? 1.0 : -1.0;
    double thr = 1e-9 * s0;
    double i0 = (s0 > 1e-300) ? 1.0 / s0 : 0.0;
    double i1 = (s1 > thr) ? 1.0 / s1 : 0.0;
    double i2 = (s2 > thr) ? d / s2 : 0.0;

    double B[3][3];
    #pragma unroll
    for (int i = 0; i < 3; ++i)
        #pragma unroll
        for (int j = 0; j < 3; ++j)
            B[i][j] = V[i][o0] * i0 * V[j][o0]
                    + V[i][o1] * i1 * V[j][o1]
                    + V[i][o2] * i2 * V[j][o2];

    double Rm[3][3];
    #pragma unroll
    for (int i = 0; i < 3; ++i)
        #pragma unroll
        for (int j = 0; j < 3; ++j)
            Rm[i][j] = B[i][0]*H[j][0] + B[i][1]*H[j][1] + B[i][2]*H[j][2];

    double com0[3], comt[3];
    #pragma unroll
    for (int a = 0; a < 3; ++a) { com0[a] = sum[a] / fn; comt[a] = sum[3+a] / fn; }

    #pragma unroll
    for (int i = 0; i < 3; ++i)
        #pragma unroll
        for (int j = 0; j < 3; ++j)
            p[3*i + j] = (float)Rm[i][j];
    #pragma unroll
    for (int i = 0; i < 3; ++i)
        p[9 + i] = (float)(comt[i] - (Rm[i][0]*com0[0] + Rm[i][1]*com0[1] + Rm[i][2]*com0[2]));
    p[12] = c0; p[13] = c1; p[14] = cs; p[15] = isf;
}

// ---------------------------------------------------------------------------
// K2: one thread per graph — Kabsch, fully parallel.
// ---------------------------------------------------------------------------
__global__ __launch_bounds__(256) void k_kabsch(const int* __restrict__ tarr) {
    int g = (int)blockIdx.x * 256 + (int)threadIdx.x;
    if (g >= GMAX) return;
    float sum[16];
    #pragma unroll
    for (int q = 0; q < 4; ++q)
        *(float4*)&sum[4*q] = ((const float4*)&g_sums[g * 16])[q];
    int n = (int)(sum[15] + 0.5f);
    int tg = tarr[g];
    float c0 = g_sched[tg];
    float c1 = g_sched[1024 + tg];
    float cs = g_sched[2048 + tg];
    float isf = g_sched[3072 + tg];
    kabsch_store(sum, n, c0, c1, cs, isf, &g_gparams[g * 16]);
}

// ---------------------------------------------------------------------------
// K3: 4 nodes/thread, coalesced float4; params reloaded only on in-thread
// graph change (rare). target = (x_t - (R x0 + tvec)) * isf.
// ---------------------------------------------------------------------------
__global__ __launch_bounds__(256) void k_final(const float* __restrict__ x0,
                                               const float* __restrict__ xt,
                                               const int* __restrict__ batch,
                                               float* __restrict__ out_tg) {
    const int t = (int)blockIdx.x * 256 + (int)threadIdx.x;
    const int4 gb = ((const int4*)batch)[t];
    const int gs[4] = {gb.x, gb.y, gb.z, gb.w};

    const float4* XA = (const float4*)x0;
    const float4* XT = (const float4*)xt;
    float ax[12], wx[12], ox[12];
    #pragma unroll
    for (int q = 0; q < 3; ++q) {
        *(float4*)&ax[4*q] = XA[3*t + q];
        *(float4*)&wx[4*q] = XT[3*t + q];
    }

    int gcur = gs[0];
    float pr[16];
    #pragma unroll
    for (int q = 0; q < 4; ++q)
        *(float4*)&pr[4*q] = ((const float4*)&g_gparams[gcur * 16])[q];

    #pragma unroll
    for (int j = 0; j < 4; ++j) {
        if (gs[j] != gcur) {
            gcur = gs[j];
            #pragma unroll
            for (int q = 0; q < 4; ++q)
                *(float4*)&pr[4*q] = ((const float4*)&g_gparams[gcur * 16])[q];
        }
        float a0 = ax[3*j], a1 = ax[3*j+1], a2 = ax[3*j+2];
        float al0 = pr[0]*a0 + pr[1]*a1 + pr[2]*a2 + pr[9];
        float al1 = pr[3]*a0 + pr[4]*a1 + pr[5]*a2 + pr[10];
        float al2 = pr[6]*a0 + pr[7]*a1 + pr[8]*a2 + pr[11];
        float isf = pr[15];
        ox[3*j]   = (wx[3*j]   - al0) * isf;
        ox[3*j+1] = (wx[3*j+1] - al1) * isf;
        ox[3*j+2] = (wx[3*j+2] - al2) * isf;
    }

    float4* OUT = (float4*)out_tg;
    #pragma unroll
    for (int q = 0; q < 3; ++q) OUT[3*t + q] = *(const float4*)&ox[4*q];
}

extern "C" void kernel_launch(void* const* d_in, const int* in_sizes, int n_in,
                              void* d_out, int out_size, void* d_ws, size_t ws_size,
                              hipStream_t stream) {
    const float* x0    = (const float*)d_in[0];
    const float* x1    = (const float*)d_in[1];
    const float* noise = (const float*)d_in[2];
    const float* beta  = (const float*)d_in[3];
    const int*   batch = (const int*)d_in[4];
    const int*   tarr  = (const int*)d_in[5];

    int N = in_sizes[4];      // 2097152
    int T = in_sizes[3];      // 1000
    int nthreads = N / 4;     // 524288 -> 2048 blocks of 256

    float* out_xt = (float*)d_out;
    float* out_tg = out_xt + (size_t)3 * N;

    k_prep<<<33, 1024, 0, stream>>>(beta, T);
    k_accum<<<nthreads / 256, 256, 0, stream>>>(x0, x1, noise, batch, tarr, out_xt);
    k_kabsch<<<GMAX / 256, 256, 0, stream>>>(tarr);
    k_final<<<nthreads / 256, 256, 0, stream>>>(x0, out_xt, batch, out_tg);
}